// Round 6
// baseline (1725.833 us; speedup 1.0000x reference)
//
#include <hip/hip_runtime.h>
#include <hip/hip_fp16.h>

// ---------------------------------------------------------------------------
// DeterministicLSTMSensorBasedForwardDynamics on MI355X (gfx950) — round 14
//
// r13 post-mortem: MTILE=32 was double-confounded — NWG=128 idled half the
// chip (Occupancy 11.5%) AND acc64+rw64 AGPRs spilled (WRITE 19 MB). r12+r13
// prove the real constraint: per-CU residency (regs+LDS ~320 KB of 704 KB)
// is maxed, scheduling levers are exhausted, and M>16 at 1 WG/CU idles CUs.
// Only remaining lever: streamed bytes per CU per step.
//
// Round 14 = PAIRED-WG N-SPLIT with per-step h exchange through L2:
//   * 256 WGs = 128 row-tiles x 2 column-halves; pair (rt,0)<->(rt,1) on the
//     same XCD (partner = bid^8 under round-robin bid%8 mapping; correctness
//     holds under any mapping, only exchange latency varies).
//   * each WG: 32 batch rows x 512 gate cols (its ch-half of all 4 gates).
//     Weights/WG = 352 blocks; resident rw 24/wave (AGPR) + Wc 14/wave (LDS)
//     = 304 -> stream 6 blocks/wave/step = 48 KB/WG/step (r8: 384 KB). 8x.
//   * acc stays 32 regs (2 M-tiles x 4 gates); 88 MFMAs/wave/step = r8's
//     matrix-pipe floor (2816 cyc/SIMD) now the dominant term.
//   * h exchange: export own 32x128 h-half (fp16, 8 KB) to ws hexp with
//     parity double-buffer; monotone agent-scope flag (release after
//     vmcnt(0)+barrier; acquire spin). Skew<=1 => parity sufficient.
//   * A-panel cols = [x 80 | own 128 | partner 128 | pad]; weights repacked
//     PER CH so K-order matches; partner cols live in kt6..10 -> exchange
//     latency hides under kt0..5. LDS 160,768 B -> 1 WG/CU -> all 256
//     co-resident -> spin is deadlock-free. Flags zeroed by repack each
//     launch (graph-replay safe).
// Prediction: dur ~120-160 us, MfmaUtil ~45-60%, FETCH ~38 MB, WRITE ~1-5 MB,
// VGPR ~124 no spill. Tripwires: WRITE >10 MB = spill/thrash; dur >261 =
// revert r8; hang = protocol bug. ws requirement: 6,373,376 bytes.
// ---------------------------------------------------------------------------

typedef _Float16 h8 __attribute__((ext_vector_type(8)));
typedef _Float16 hv4 __attribute__((ext_vector_type(4)));
typedef float f4 __attribute__((ext_vector_type(4)));

#define NB    4096
#define TSEQ  50
#define DOBS  64
#define DACT  16
#define HD    256
#define DOUT  64
#define NL    5

#define NKT   11        // K-tiles of 32 covering 352 = 80 x + 128 own + 128 partner + 16 pad
#define AROW  360       // LDS A-row stride in halves
#define MTILE 32
#define NWG   256       // 128 row-tiles x 2 col-halves
#define NTHR  512       // 8 waves

// ws layout in halves (written by repack_kernel):
//   [0, 704*512)        LSTM weights, ch=0 permutation (x|h0..127|h128..255)
//   [704*512, 1408*512) LSTM weights, ch=1 permutation (x|h128..255|h0..127)
//   [1408*512, 2048*512) MLP [5][256][256]
//   [2048*512, 2112*512) Wout
//   [2112*512, +4 MB)    hexp[fi=rt*2+ch][parity][32][128] fp16
//   then 16 KB flags: uint flags[fi*16]
#define WS_COPY   (704 * 512)
#define WS_MLP    (1408 * 512)
#define WS_WOUT   (2048 * 512)
#define WS_HEXP   (2112 * 512)
#define WS_FLAGS_B (2112 * 1024 + 4194304)   // byte offset of flags
// total ws bytes = 6,373,376

// LDS layout (halves): As0 | As1 | Wcache(8 waves x WCB blocks)
#define LDS_AS     (MTILE * AROW)      // 11520 per panel
#define LDS_WCOFF  (2 * LDS_AS)        // 23040
#define WCB        14                  // LDS blocks/wave: kt6..8 x g + kt9 g0,g1
#define LDS_HALVES (LDS_WCOFF + 8 * WCB * 512)   // 80384
#define LDS_BYTES  (LDS_HALVES * 2)              // 160768 (<= 163840) -> 1 WG/CU
static_assert(LDS_BYTES <= 160 * 1024, "LDS overflow");

// Streamed blocks/wave: kt9 g2,g3 (slots 0,1) + kt10 g0..3 (slots 2..5).
// Slot<->block is STATIC (same weights every step): consume, refill same
// address for next step -> cover = one full step.
#define SB_P 6

// LDS-only barrier (does not drain vmcnt): stream/x/partner loads target
// private VGPRs and are synchronized by their own waits.
__device__ __forceinline__ void lds_barrier() {
  asm volatile("s_waitcnt lgkmcnt(0)\n\ts_barrier" ::: "memory");
}
// Full barrier: drains vmcnt too (needed before flag release: all threads'
// h-export stores must be L2-visible before tid0 publishes the flag).
__device__ __forceinline__ void full_barrier() {
  asm volatile("s_waitcnt vmcnt(0) lgkmcnt(0)\n\ts_barrier" ::: "memory");
}

// (g,kt) -> block offset (halves) rel. to wave base (nb*NKT*512) within a copy
__device__ constexpr int boff(int g, int kt) { return (g * 16 * NKT + kt) * 512; }

// --------------------------- weight repack ---------------------------------
__global__ void __launch_bounds__(256) repack_kernel(
    const float* __restrict__ Wi, const float* __restrict__ Wh,
    const float* __restrict__ mlpW, const float* __restrict__ Wout,
    _Float16* __restrict__ wsW, unsigned int* __restrict__ flags)
{
  const int gt  = blockIdx.x * 256 + threadIdx.x;
  const int gb  = gt >> 6;
  const int l   = gt & 63;
  const int l15 = l & 15;
  const int kb  = (l >> 4) * 8;
  if (gb < 1408) {                      // LSTM, per-ch permuted copies
    const int ch = (gb >= 704) ? 1 : 0;
    const int g2 = gb - ch * 704;
    const int nt = g2 / NKT, kt = g2 - nt * NKT;
    const int n  = nt * 16 + l15;
    h8 v;
#pragma unroll
    for (int j = 0; j < 8; ++j) {
      const int kk = kt * 32 + kb + j;   // permuted K row
      float s = 0.f;
      if (kk < 80)       s = Wi[kk * 1024 + n];
      else if (kk < 208) s = Wh[(ch * 128 + (kk - 80)) * 1024 + n];        // own half
      else if (kk < 336) s = Wh[((1 - ch) * 128 + (kk - 208)) * 1024 + n]; // partner half
      v[j] = (_Float16)s;
    }
    *(h8*)&wsW[(size_t)gb * 512 + l * 8] = v;
  } else if (gb < 2048) {               // MLP layer weights [5][256][256]
    const int b2 = gb - 1408;
    const int L  = b2 >> 7, rr = b2 & 127;
    const int nt = rr >> 3, kt = rr & 7;
    const int n  = nt * 16 + l15;
    h8 v;
#pragma unroll
    for (int j = 0; j < 8; ++j) {
      const int k = kt * 32 + kb + j;
      v[j] = (_Float16)mlpW[(size_t)L * 65536 + k * 256 + n];
    }
    *(h8*)&wsW[(size_t)gb * 512 + l * 8] = v;
  } else if (gb < 2112) {               // Wout [256][64]
    const int b3 = gb - 2048;
    const int nt = b3 >> 3, kt = b3 & 7;
    const int n  = nt * 16 + l15;
    h8 v;
#pragma unroll
    for (int j = 0; j < 8; ++j) {
      const int k = kt * 32 + kb + j;
      v[j] = (_Float16)Wout[k * 64 + n];
    }
    *(h8*)&wsW[(size_t)gb * 512 + l * 8] = v;
  } else if (gb < 2116) {               // zero the 256 exchange flags
    const int idx = (gb - 2112) * 64 + l;   // 0..255
    flags[idx * 16] = 0u;
  }
}

// ------------------------------ main kernel --------------------------------
__global__ void __launch_bounds__(NTHR, 2) lstm_kernel(
    const float* __restrict__ traj, const float* __restrict__ acts,
    const float* __restrict__ bh,   const float* __restrict__ mlpb,
    const float* __restrict__ bout, const _Float16* __restrict__ wsW,
    _Float16* __restrict__ hexp, unsigned int* __restrict__ flags,
    float* __restrict__ out)
{
  extern __shared__ __align__(16) _Float16 lds[];
  _Float16* As0 = lds;
  _Float16* As1 = lds + LDS_AS;
  _Float16* Wc  = lds + LDS_WCOFF;

  const int tid = threadIdx.x;
  const int w   = tid >> 6;        // wave 0..7
  const int l   = tid & 63;
  const int l15 = l & 15;
  const int lq  = l >> 4;
  const int bid = blockIdx.x;
  const int ch  = (bid >> 3) & 1;                 // column half
  const int rt  = (bid & 7) | ((bid >> 4) << 3);  // row tile 0..127 (partner = bid^8, same XCD slot)
  const int fi  = rt * 2 + ch, fj = rt * 2 + (1 - ch);
  const int rbase = rt * MTILE;
  const int nb  = ch * 8 + w;      // col-group within each gate (0..15)

  // Zero both A panels (h starts 0; partner region zero for t=0; pad stays 0).
  for (int i = tid; i < 2 * LDS_AS; i += NTHR) lds[i] = (_Float16)0.f;

  const _Float16* wcopy = wsW + (size_t)ch * WS_COPY;

  // LDS-resident: 14 blocks/wave = kt6..8 x g0..3 (12) + kt9 g0,g1 (2)
#pragma unroll
  for (int j = 0; j < 12; ++j) {
    const int g = j & 3, kt = 6 + (j >> 2);
    const h8 v = *(const h8*)&wcopy[(size_t)nb * NKT * 512 + boff(g, kt) + l * 8];
    *(h8*)&Wc[(w * WCB + j) * 512 + l * 8] = v;
  }
#pragma unroll
  for (int g = 0; g < 2; ++g) {
    const h8 v = *(const h8*)&wcopy[(size_t)nb * NKT * 512 + boff(g, 9) + l * 8];
    *(h8*)&Wc[(w * WCB + 12 + g) * 512 + l * 8] = v;
  }

  // Register-resident: 24 blocks/wave = kt0..5 x g0..3 — AGPR-backed.
  h8 rw[24];
#pragma unroll
  for (int kt = 0; kt < 6; ++kt)
#pragma unroll
    for (int g = 0; g < 4; ++g)
      rw[kt * 4 + g] = *(const h8*)&wcopy[(size_t)nb * NKT * 512 + boff(g, kt) + l * 8];

  // Persistent cell state (2 M-tiles x 4 rows) + biases (canonical cols)
  float c[2][4];
#pragma unroll
  for (int m = 0; m < 2; ++m)
#pragma unroll
    for (int r = 0; r < 4; ++r) c[m][r] = 0.f;

  float bias[4];
#pragma unroll
  for (int g = 0; g < 4; ++g) bias[g] = bh[g * 256 + ch * 128 + w * 16 + l15];

  __syncthreads();

  // Stage x_0 into As0 cols 0..79: thread -> (row tid>>4, quad tid&15)
  {
    const int r = tid >> 4, q = tid & 15;
    const float4 v = *(const float4*)&traj[(size_t)(rbase + r) * (TSEQ * DOBS) + q * 4];
    hv4 hx = { (_Float16)v.x, (_Float16)v.y, (_Float16)v.z, (_Float16)v.w };
    *(hv4*)&As0[r * AROW + q * 4] = hx;
    As0[r * AROW + 64 + q] = (_Float16)acts[(size_t)(rbase + r) * (TSEQ * DACT) + q];
  }
  __syncthreads();

  unsigned long long wbits = (unsigned long long)(const void*)wcopy;

  // Static 6-slot stream ring: slots 0,1 = (kt9,g2),(kt9,g3); 2..5 = (kt10,g).
  h8 sb[SB_P];
  {
    const _Float16* wlb0 = wcopy + (size_t)nb * NKT * 512 + l * 8;
    sb[0] = *(const h8*)&wlb0[boff(2, 9)];
    sb[1] = *(const h8*)&wlb0[boff(3, 9)];
#pragma unroll
    for (int g = 0; g < 4; ++g) sb[2 + g] = *(const h8*)&wlb0[boff(g, 10)];
  }

  auto step = [&](int t, const _Float16* buf, _Float16* nbuf) {
    // Memory clobber: stream reloads can't be CSE'd across steps; rw[] can't
    // be rematerialized from wsW.
    asm volatile("" : "+s"(wbits) : : "memory");
    const _Float16* wlb = (const _Float16*)wbits + (size_t)nb * NKT * 512 + l * 8;

    const int rr = tid >> 4, cbk = tid & 15;

    // x(t+1): issue loads now, store to LDS at end of step.
    float4 xv; float xa;
    const bool havex = (t + 1 < TSEQ);
    if (havex) {
      xv = *(const float4*)&traj[(size_t)(rbase + rr) * (TSEQ * DOBS) + (t + 1) * DOBS + cbk * 4];
      xa = acts[(size_t)(rbase + rr) * (TSEQ * DACT) + (t + 1) * DACT + cbk];
    }

    // Partner h(t): spin (acquire) then issue the 8 KB load; consumed at kt6+.
    h8 pv;
    if (t > 0) {
      const unsigned int* pf = flags + fj * 16;
      while (__hip_atomic_load(pf, __ATOMIC_ACQUIRE, __HIP_MEMORY_SCOPE_AGENT) < (unsigned)t)
        __builtin_amdgcn_s_sleep(2);
      pv = *(const h8*)&hexp[(((size_t)fj * 2 + (t & 1)) * 32 + rr) * 128 + cbk * 8];
    }

    f4 acc[2][4];   // [m][g]
#pragma unroll
    for (int m = 0; m < 2; ++m)
#pragma unroll
      for (int g = 0; g < 4; ++g) acc[m][g] = f4{0.f, 0.f, 0.f, 0.f};

    // ---- kt0..5: x + own-h, all operands register-resident ----
#pragma unroll
    for (int kt = 0; kt < 6; ++kt) {
      const h8 a0 = *(const h8*)&buf[l15 * AROW + kt * 32 + lq * 8];
      const h8 a1 = *(const h8*)&buf[(16 + l15) * AROW + kt * 32 + lq * 8];
#pragma unroll
      for (int g = 0; g < 4; ++g) {
        acc[0][g] = __builtin_amdgcn_mfma_f32_16x16x32_f16(a0, rw[kt * 4 + g], acc[0][g], 0, 0, 0);
        acc[1][g] = __builtin_amdgcn_mfma_f32_16x16x32_f16(a1, rw[kt * 4 + g], acc[1][g], 0, 0, 0);
      }
    }

    // ---- publish partner h(t) into this panel's cols 208..335 ----
    if (t > 0) *(h8*)&buf[rr * AROW + 208 + cbk * 8] = pv;
    lds_barrier();

    // ---- kt6..10: own tail + partner region ----
#pragma unroll
    for (int kt = 6; kt < NKT; ++kt) {
      const h8 a0 = *(const h8*)&buf[l15 * AROW + kt * 32 + lq * 8];
      const h8 a1 = *(const h8*)&buf[(16 + l15) * AROW + kt * 32 + lq * 8];
#pragma unroll
      for (int g = 0; g < 4; ++g) {
        h8 bf;
        if (kt < 9)       bf = *(const h8*)&Wc[(w * WCB + (kt - 6) * 4 + g) * 512 + l * 8];
        else if (kt == 9) {
          if (g < 2) bf = *(const h8*)&Wc[(w * WCB + 12 + g) * 512 + l * 8];
          else { bf = sb[g - 2]; sb[g - 2] = *(const h8*)&wlb[boff(g, 9)]; }
        } else { bf = sb[2 + g]; sb[2 + g] = *(const h8*)&wlb[boff(g, 10)]; }
        acc[0][g] = __builtin_amdgcn_mfma_f32_16x16x32_f16(a0, bf, acc[0][g], 0, 0, 0);
        acc[1][g] = __builtin_amdgcn_mfma_f32_16x16x32_f16(a1, bf, acc[1][g], 0, 0, 0);
      }
    }

    // ---- cell update (fused-rcp) + LDS own-store + global export ----
    const float KE = -1.44269504088896f;
    _Float16* hx = &hexp[((size_t)fi * 2 + ((t + 1) & 1)) * 32 * 128];
#pragma unroll
    for (int m = 0; m < 2; ++m)
#pragma unroll
      for (int r = 0; r < 4; ++r) {
        const float zi = acc[m][0][r] + bias[0];
        const float zf = acc[m][1][r] + bias[1];
        const float zg = acc[m][2][r] + bias[2];
        const float zo = acc[m][3][r] + bias[3];
        const float ei = __builtin_amdgcn_exp2f(zi * KE);
        const float ef = __builtin_amdgcn_exp2f(zf * KE);
        const float eg = __builtin_amdgcn_exp2f(zg * KE);
        const float eo = __builtin_amdgcn_exp2f(zo * KE);
        const float fg = __builtin_amdgcn_rcpf(1.f + ef);
        const float igg = zg * __builtin_amdgcn_rcpf((1.f + ei) * (1.f + eg));
        const float cn = fg * c[m][r] + igg;
        c[m][r] = cn;
        const float ec = __builtin_amdgcn_exp2f(cn * KE);
        const float hn = cn * __builtin_amdgcn_rcpf((1.f + eo) * (1.f + ec));
        const int row = m * 16 + lq * 4 + r;
        nbuf[row * AROW + 80 + w * 16 + l15] = (_Float16)hn;   // own region
        hx[row * 128 + w * 16 + l15] = (_Float16)hn;           // export
      }

    // Deferred x(t+1) store into nbuf cols 0..79.
    if (havex) {
      hv4 hv = { (_Float16)xv.x, (_Float16)xv.y, (_Float16)xv.z, (_Float16)xv.w };
      *(hv4*)&nbuf[rr * AROW + cbk * 4] = hv;
      nbuf[rr * AROW + 64 + cbk] = (_Float16)xa;
    }

    // Drain exports (vmcnt) + LDS, then publish flag t+1.
    full_barrier();
    if (tid == 0)
      __hip_atomic_store(flags + fi * 16, (unsigned)(t + 1),
                         __ATOMIC_RELEASE, __HIP_MEMORY_SCOPE_AGENT);
  };

#pragma unroll 1
  for (int t = 0; t < TSEQ; t += 2) {
    step(t, As0, As1);
    step(t + 1, As1, As0);
  }

  // ---------------- MLP head (M-split: this WG does rows ch*16..+16) -------
  // Fetch partner h(50) and build canonical-order input in As1 cols 0..255.
  {
    const unsigned int* pf = flags + fj * 16;
    while (__hip_atomic_load(pf, __ATOMIC_ACQUIRE, __HIP_MEMORY_SCOPE_AGENT) < (unsigned)TSEQ)
      __builtin_amdgcn_s_sleep(2);
    const int rr = tid >> 4, cbk = tid & 15;
    const h8 pv = *(const h8*)&hexp[(((size_t)fj * 2 + (TSEQ & 1)) * 32 + rr) * 128 + cbk * 8];
    *(h8*)&As1[rr * AROW + (1 - ch) * 128 + cbk * 8] = pv;     // partner canonical
    if (tid < 256) {                                           // own canonical
      const int r2 = ch * 16 + (tid >> 4), cb2 = tid & 15;
      const h8 ov = *(const h8*)&As0[r2 * AROW + 80 + cb2 * 8];
      *(h8*)&As1[r2 * AROW + ch * 128 + cb2 * 8] = ov;
    }
  }
  lds_barrier();

#pragma unroll 1
  for (int L = 0; L < NL; ++L) {
    const _Float16* in = (L & 1) ? As0 : As1;
    _Float16*       ob = (L & 1) ? As1 : As0;
    const _Float16* wl = wsW + WS_MLP + (size_t)L * (128 * 512);
    float bcol[2];
    bcol[0] = mlpb[L * HD + w * 32 + l15];
    bcol[1] = mlpb[L * HD + w * 32 + 16 + l15];

    f4 acc[2];
    acc[0] = f4{0.f, 0.f, 0.f, 0.f};
    acc[1] = f4{0.f, 0.f, 0.f, 0.f};
#pragma unroll
    for (int kt = 0; kt < 8; ++kt) {
      const h8 a0 = *(const h8*)&in[(ch * 16 + l15) * AROW + kt * 32 + lq * 8];
#pragma unroll
      for (int cb = 0; cb < 2; ++cb) {
        const h8 bf = *(const h8*)&wl[(size_t)((w * 2 + cb) * 8 + kt) * 512 + l * 8];
        acc[cb] = __builtin_amdgcn_mfma_f32_16x16x32_f16(a0, bf, acc[cb], 0, 0, 0);
      }
    }
#pragma unroll
    for (int cb = 0; cb < 2; ++cb)
#pragma unroll
      for (int r = 0; r < 4; ++r) {
        const float z = acc[cb][r] + bcol[cb];
        const float ez = __builtin_amdgcn_exp2f(z * -1.44269504088896f);
        ob[(ch * 16 + lq * 4 + r) * AROW + w * 32 + cb * 16 + l15] =
            (_Float16)(z * __builtin_amdgcn_rcpf(1.f + ez));
      }
    __syncthreads();
  }

  // Output layer: final activations in As0 (NL=5 odd). N=64 -> waves 0..3.
  if (w < 4) {
    const _Float16* wo = wsW + WS_WOUT;
    const float bo = bout[w * 16 + l15];
    f4 acc = f4{0.f, 0.f, 0.f, 0.f};
#pragma unroll
    for (int kt = 0; kt < 8; ++kt) {
      const h8 a0 = *(const h8*)&As0[(ch * 16 + l15) * AROW + kt * 32 + lq * 8];
      const h8 bf = *(const h8*)&wo[(size_t)(w * 8 + kt) * 512 + l * 8];
      acc = __builtin_amdgcn_mfma_f32_16x16x32_f16(a0, bf, acc, 0, 0, 0);
    }
#pragma unroll
    for (int r = 0; r < 4; ++r)
      out[(size_t)(rbase + ch * 16 + lq * 4 + r) * DOUT + w * 16 + l15] = acc[r] + bo;
  }
}

// ------------------------------- launcher ----------------------------------
extern "C" void kernel_launch(void* const* d_in, const int* in_sizes, int n_in,
                              void* d_out, int out_size, void* d_ws, size_t ws_size,
                              hipStream_t stream)
{
  const float* traj = (const float*)d_in[0];
  const float* acts = (const float*)d_in[1];
  const float* Wi   = (const float*)d_in[2];
  const float* Wh   = (const float*)d_in[3];
  const float* bh   = (const float*)d_in[4];
  const float* mlpW = (const float*)d_in[5];
  const float* mlpb = (const float*)d_in[6];
  const float* Wout = (const float*)d_in[7];
  const float* bout = (const float*)d_in[8];
  _Float16* wsW = (_Float16*)d_ws;   // needs 6,373,376 bytes of workspace
  _Float16* hexp = wsW + WS_HEXP;
  unsigned int* flags = (unsigned int*)((char*)d_ws + WS_FLAGS_B);

  (void)hipFuncSetAttribute((const void*)lstm_kernel,
                            hipFuncAttributeMaxDynamicSharedMemorySize, LDS_BYTES);

  repack_kernel<<<529, 256, 0, stream>>>(Wi, Wh, mlpW, Wout, wsW, flags);
  lstm_kernel<<<NWG, NTHR, LDS_BYTES, stream>>>(traj, acts, bh, mlpb, bout,
                                                wsW, hexp, flags, (float*)d_out);
}

// Round 8
// 332.182 us; speedup vs baseline: 5.1954x; 5.1954x over previous
//
#include <hip/hip_runtime.h>
#include <hip/hip_fp16.h>

// ---------------------------------------------------------------------------
// DeterministicLSTMSensorBasedForwardDynamics on MI355X (gfx950) — round 16
// (= round 15 with the compile fix: __builtin_nontemporal_load rejects HIP's
//  float4 struct; use the native ext_vector f4 type for those loads.)
//
// Theory (r15): the 65 MB fp32 activation stream (traj/acts) continuously
// EVICTS the 704 KB weight set from the 4 MB per-XCD L2s -> weight stream
// falls to L3 (~400-600 cyc), at the edge of the ring's ~620-cyc cover ->
// chronic stalls (the measured ~65% stall fraction). FETCH stays 37.6 MB
// because L3 refills don't count as HBM fetch.
//
// Round 16 = r8 structure + two surgical edits:
//   1. NONTEMPORAL loads for traj/acts and stores for out: activations no
//      longer allocate in L2 -> weights stay L2-resident -> stream latency
//      ~200-300 cyc, well under the ring's cover.
//   2. fused-rcp cell update (r11-verified numerics, absmax unchanged).
// Prediction: theory right -> dur ~190-220 us, MfmaUtil ~30-35%, FETCH up to
// ~55-65 MB, WRITE ~1 MB. Null (255-270) -> weights already cache-resident
// -> structural operand-delivery bound at fp16 -> ROOFLINE next round.
// ---------------------------------------------------------------------------

typedef _Float16 h8 __attribute__((ext_vector_type(8)));
typedef _Float16 hv4 __attribute__((ext_vector_type(4)));
typedef float f4 __attribute__((ext_vector_type(4)));

#define NB    4096
#define TSEQ  50
#define DOBS  64
#define DACT  16
#define HD    256
#define DOUT  64
#define NL    5

#define NKT   11        // K-tiles of 32 covering 352 = 80 (x) + 256 (h) + 16 pad
#define AROW  360       // LDS A-row stride in halves
#define MTILE 16
#define NWG   (NB / MTILE)   // 256
#define NTHR  512            // 8 waves

// ws layout in halves (written by repack_kernel)
#define WS_MLP   (704 * 512)
#define WS_WOUT  (WS_MLP + 640 * 512)

// LDS layout (halves): As0 | As1 | Wcache(8 waves x WCB blocks)
#define LDS_AS     (MTILE * AROW)      // 5760 per panel
#define LDS_WCOFF  (2 * LDS_AS)        // 11520
#define WCB        16                  // LDS-resident blocks per wave (cb0 kt6..9)
#define LDS_HALVES (LDS_WCOFF + 8 * WCB * 512)   // 77056
#define LDS_BYTES  (LDS_HALVES * 2)              // 154112  (<= 160 KiB)
static_assert(LDS_BYTES <= 160 * 1024, "LDS overflow");

// streaming: cb1 kt0..10 (44) + cb0 kt10 (4) = 48 blocks/wave/step,
// through an 8-slot ring that persists ACROSS steps (48 % 8 == 0).
#define SB_P     8
#define NSTREAM  48

// Barrier that does NOT drain vmcnt: cross-wave data dependencies at the
// t-loop barrier are ds_write-only (h and x panels), covered by lgkmcnt(0).
// In-flight global loads (stream ring, x prefetch) target private VGPRs and
// are synchronized by their own vmcnt-before-use waits -> legal to keep
// flying across s_barrier.
__device__ __forceinline__ void lds_barrier() {
  asm volatile("s_waitcnt lgkmcnt(0)\n\ts_barrier" ::: "memory");
}

// sigmoid via native v_exp_f32 + v_rcp_f32 (1-ulp; fp16 weights dominate err).
__device__ __forceinline__ float sigf(float x) {
  const float e = __builtin_amdgcn_exp2f(x * -1.44269504088896f);
  return __builtin_amdgcn_rcpf(1.f + e);
}

// stream order c -> block offset (halves) rel. to wave base (w*2*NKT*512):
//   c in [0,44):  cb1, kt = c>>2, g = c&3   -> ((g*16+1)*NKT + kt)*512
//   c in [44,48): cb0 kt10, g = c-44        -> ((g*16+0)*NKT + 10)*512
__device__ constexpr int soff(int c) {
  if (c < 44) { const int g = c & 3, kt = c >> 2; return ((g * 16 + 1) * NKT + kt) * 512; }
  const int g = c - 44; return ((g * 16) * NKT + 10) * 512;
}

// --------------------------- weight repack ---------------------------------
__global__ void __launch_bounds__(256) repack_kernel(
    const float* __restrict__ Wi, const float* __restrict__ Wh,
    const float* __restrict__ mlpW, const float* __restrict__ Wout,
    _Float16* __restrict__ wsW)
{
  const int gt  = blockIdx.x * 256 + threadIdx.x;
  const int gb  = gt >> 6;
  const int l   = gt & 63;
  const int l15 = l & 15;
  const int kb  = (l >> 4) * 8;
  h8 v;
  if (gb < 704) {                       // LSTM: Wcat[k][n], k<80 -> Wi, k<336 -> Wh, else 0
    const int nt = gb / NKT, kt = gb - nt * NKT;
    const int n  = nt * 16 + l15;
#pragma unroll
    for (int j = 0; j < 8; ++j) {
      const int k = kt * 32 + kb + j;
      float s = 0.f;
      if (k < 80)       s = Wi[k * 1024 + n];
      else if (k < 336) s = Wh[(k - 80) * 1024 + n];
      v[j] = (_Float16)s;
    }
  } else if (gb < 1344) {               // MLP layer weights [5][256][256]
    const int b2 = gb - 704;
    const int L  = b2 >> 7, rr = b2 & 127;
    const int nt = rr >> 3, kt = rr & 7;
    const int n  = nt * 16 + l15;
#pragma unroll
    for (int j = 0; j < 8; ++j) {
      const int k = kt * 32 + kb + j;
      v[j] = (_Float16)mlpW[(size_t)L * 65536 + k * 256 + n];
    }
  } else {                              // Wout [256][64]
    const int b3 = gb - 1344;
    const int nt = b3 >> 3, kt = b3 & 7;
    const int n  = nt * 16 + l15;
#pragma unroll
    for (int j = 0; j < 8; ++j) {
      const int k = kt * 32 + kb + j;
      v[j] = (_Float16)Wout[k * 64 + n];
    }
  }
  *(h8*)&wsW[(size_t)gb * 512 + l * 8] = v;
}

// ------------------------------ main kernel --------------------------------
__global__ void __launch_bounds__(NTHR, 2) lstm_kernel(
    const float* __restrict__ traj, const float* __restrict__ acts,
    const float* __restrict__ bh,   const float* __restrict__ mlpb,
    const float* __restrict__ bout, const _Float16* __restrict__ wsW,
    float* __restrict__ out)
{
  extern __shared__ __align__(16) _Float16 lds[];
  _Float16* As0 = lds;
  _Float16* As1 = lds + LDS_AS;
  _Float16* Wc  = lds + LDS_WCOFF;

  const int tid = threadIdx.x;
  const int w   = tid >> 6;        // wave 0..7: owns h-cols [32w, 32w+32)
  const int l   = tid & 63;
  const int l15 = l & 15;
  const int lq  = l >> 4;
  const int rbase = blockIdx.x * MTILE;

  // Zero both A panels (h starts 0; pad cols 336..359 stay 0 forever).
  for (int i = tid; i < 2 * LDS_AS; i += NTHR) lds[i] = (_Float16)0.f;

  // LDS-resident: 16 blocks/wave = (cb0, kt6..9, g0..3)
#pragma unroll
  for (int j = 0; j < WCB; ++j) {
    const int g = j & 3, kt = 6 + (j >> 2);
    const h8 v = *(const h8*)&wsW[(size_t)((g * 16 + w * 2) * NKT + kt) * 512 + l * 8];
    *(h8*)&Wc[(w * WCB + j) * 512 + l * 8] = v;
  }

  // Register-resident: 24 blocks/wave = (cb0, kt0..5, g0..3) — AGPR-backed.
  h8 rw[24];
#pragma unroll
  for (int kt = 0; kt < 6; ++kt)
#pragma unroll
    for (int g = 0; g < 4; ++g)
      rw[kt * 4 + g] = *(const h8*)&wsW[(size_t)((g * 16 + w * 2) * NKT + kt) * 512 + l * 8];

  // Persistent cell state + biases
  float c[2][4];
#pragma unroll
  for (int cb = 0; cb < 2; ++cb)
#pragma unroll
    for (int r = 0; r < 4; ++r) c[cb][r] = 0.f;

  float bias[4][2];
#pragma unroll
  for (int g = 0; g < 4; ++g) {
    bias[g][0] = bh[g * 256 + w * 32 + l15];
    bias[g][1] = bh[g * 256 + w * 32 + 16 + l15];
  }

  __syncthreads();

  // Stage x_0 into As0 cols 0..79 (traj via waves 0-3, acts via waves 4-7).
  // Nontemporal: activations must NOT evict the weight set from L2.
  if (tid < 256) {
    const int r = tid >> 4, q = tid & 15;
    const f4 v = __builtin_nontemporal_load(
        (const f4*)&traj[(size_t)(rbase + r) * (TSEQ * DOBS) + q * 4]);
    hv4 hx = { (_Float16)v.x, (_Float16)v.y, (_Float16)v.z, (_Float16)v.w };
    *(hv4*)&As0[r * AROW + q * 4] = hx;
  } else {
    const int r = (tid - 256) >> 4, q = (tid - 256) & 15;
    As0[r * AROW + 64 + q] = (_Float16)__builtin_nontemporal_load(
        &acts[(size_t)(rbase + r) * (TSEQ * DACT) + q]);
  }
  __syncthreads();

  unsigned long long wbits = (unsigned long long)(const void*)wsW;

  // Persistent 8-slot stream ring. Primed once here; thereafter each step's
  // last 8 refills prime the next step (stream order periodic mod 48).
  h8 sb[SB_P];
  {
    const _Float16* wlb0 = wsW + (size_t)(w * 2 * NKT) * 512 + l * 8;
#pragma unroll
    for (int cc = 0; cc < SB_P; ++cc) sb[cc] = *(const h8*)&wlb0[soff(cc)];
  }

  auto step = [&](int t, const _Float16* buf, _Float16* nbuf) {
    // Memory clobber: stream loads can't be hoisted/CSE'd across steps and
    // rw[] can't be legally rematerialized from wsW.
    asm volatile("" : "+s"(wbits) : : "memory");
    const _Float16* wst = (const _Float16*)wbits;
    const _Float16* wlb = wst + (size_t)(w * 2 * NKT) * 512 + l * 8;

    // x(t+1): load to registers now (nontemporal), store to LDS at end.
    f4 xv; float xa;
    const bool havex = (t + 1 < TSEQ);
    if (havex) {
      if (tid < 256) {
        const int r = tid >> 4, q = tid & 15;
        xv = __builtin_nontemporal_load(
            (const f4*)&traj[(size_t)(rbase + r) * (TSEQ * DOBS) + (t + 1) * DOBS + q * 4]);
      } else {
        const int r = (tid - 256) >> 4, q = (tid - 256) & 15;
        xa = __builtin_nontemporal_load(
            &acts[(size_t)(rbase + r) * (TSEQ * DACT) + (t + 1) * DACT + q]);
      }
    }

    // ---------------- fused K-loop: cb0 (on-chip) + cb1 (streamed) ---------
    f4 acc0[4], acc1[4];
#pragma unroll
    for (int g = 0; g < 4; ++g) {
      acc0[g] = f4{0.f, 0.f, 0.f, 0.f};
      acc1[g] = f4{0.f, 0.f, 0.f, 0.f};
    }

#pragma unroll
    for (int kt = 0; kt < NKT; ++kt) {
      const h8 a0 = *(const h8*)&buf[l15 * AROW + kt * 32 + lq * 8];
#pragma unroll
      for (int g = 0; g < 4; ++g) {
        // cb0 fragment: registers (kt<6), LDS cache (kt6..9), stream (kt10,
        // ring slots 4..7 = positions 44..47, refilled at kt9).
        h8 bf0;
        if (kt < 6)       bf0 = rw[kt * 4 + g];
        else if (kt < 10) bf0 = *(const h8*)&Wc[(w * WCB + (kt - 6) * 4 + g) * 512 + l * 8];
        else              bf0 = sb[4 + g];
        acc0[g] = __builtin_amdgcn_mfma_f32_16x16x32_f16(a0, bf0, acc0[g], 0, 0, 0);

        // cb1 fragment: stream position cc; refill slot with position cc+8
        // (mod 48 -> the last 8 refills fetch NEXT step's first blocks).
        const int cc = kt * 4 + g;
        acc1[g] = __builtin_amdgcn_mfma_f32_16x16x32_f16(a0, sb[cc % SB_P], acc1[g], 0, 0, 0);
        sb[cc % SB_P] = *(const h8*)&wlb[soff((cc + SB_P) % NSTREAM)];
        if (kt == 10) {   // also re-prime the cb0-kt10 slots for next step
          sb[4 + g] = *(const h8*)&wlb[soff(4 + g)];
        }
      }
    }

    // ---------------- cell update (fused-rcp: 5 exp + 3 rcp per chain) -----
    const float KE = -1.44269504088896f;   // -log2(e)
    {
      const int colh = 80 + w * 32 + l15;   // cb=0
#pragma unroll
      for (int r = 0; r < 4; ++r) {
        const float zi = acc0[0][r] + bias[0][0];
        const float zf = acc0[1][r] + bias[1][0];
        const float zg = acc0[2][r] + bias[2][0];
        const float zo = acc0[3][r] + bias[3][0];
        const float ei = __builtin_amdgcn_exp2f(zi * KE);
        const float ef = __builtin_amdgcn_exp2f(zf * KE);
        const float eg = __builtin_amdgcn_exp2f(zg * KE);
        const float eo = __builtin_amdgcn_exp2f(zo * KE);
        const float fg = __builtin_amdgcn_rcpf(1.f + ef);
        const float igg = zg * __builtin_amdgcn_rcpf((1.f + ei) * (1.f + eg)); // i*g
        const float cn = fg * c[0][r] + igg;
        c[0][r] = cn;
        const float ec = __builtin_amdgcn_exp2f(cn * KE);
        const float hn = cn * __builtin_amdgcn_rcpf((1.f + eo) * (1.f + ec)); // o*silu(c)
        nbuf[(lq * 4 + r) * AROW + colh] = (_Float16)hn;
      }
    }
    {
      const int colh = 80 + w * 32 + 16 + l15;   // cb=1
#pragma unroll
      for (int r = 0; r < 4; ++r) {
        const float zi = acc1[0][r] + bias[0][1];
        const float zf = acc1[1][r] + bias[1][1];
        const float zg = acc1[2][r] + bias[2][1];
        const float zo = acc1[3][r] + bias[3][1];
        const float ei = __builtin_amdgcn_exp2f(zi * KE);
        const float ef = __builtin_amdgcn_exp2f(zf * KE);
        const float eg = __builtin_amdgcn_exp2f(zg * KE);
        const float eo = __builtin_amdgcn_exp2f(zo * KE);
        const float fg = __builtin_amdgcn_rcpf(1.f + ef);
        const float igg = zg * __builtin_amdgcn_rcpf((1.f + ei) * (1.f + eg));
        const float cn = fg * c[1][r] + igg;
        c[1][r] = cn;
        const float ec = __builtin_amdgcn_exp2f(cn * KE);
        const float hn = cn * __builtin_amdgcn_rcpf((1.f + eo) * (1.f + ec));
        nbuf[(lq * 4 + r) * AROW + colh] = (_Float16)hn;
      }
    }

    // Deferred x(t+1) store into nbuf cols 0..79.
    if (havex) {
      if (tid < 256) {
        const int r = tid >> 4, q = tid & 15;
        hv4 hx = { (_Float16)xv.x, (_Float16)xv.y, (_Float16)xv.z, (_Float16)xv.w };
        *(hv4*)&nbuf[r * AROW + q * 4] = hx;
      } else {
        const int r = (tid - 256) >> 4, q = (tid - 256) & 15;
        nbuf[r * AROW + 64 + q] = (_Float16)xa;
      }
    }
  };

#pragma unroll 1
  for (int t = 0; t < TSEQ; t += 2) {
    step(t, As0, As1);
    lds_barrier();           // LDS-only: stream ring stays in flight
    step(t + 1, As1, As0);
    lds_barrier();
  }

  // ---------------- MLP head ----------------
  // Final h in As0 cols 80..335. Move to As1 cols 0..255.
  for (int i = tid; i < MTILE * HD; i += NTHR) {
    const int r = i >> 8, cc = i & 255;
    As1[r * AROW + cc] = As0[r * AROW + 80 + cc];
  }
  __syncthreads();

#pragma unroll 1
  for (int L = 0; L < NL; ++L) {
    const _Float16* in = (L & 1) ? As0 : As1;
    _Float16*       ob = (L & 1) ? As1 : As0;
    const _Float16* wl = wsW + WS_MLP + (size_t)L * (128 * 512);
    float bcol[2];
    bcol[0] = mlpb[L * HD + w * 32 + l15];
    bcol[1] = mlpb[L * HD + w * 32 + 16 + l15];

    f4 acc[2];
    acc[0] = f4{0.f, 0.f, 0.f, 0.f};
    acc[1] = f4{0.f, 0.f, 0.f, 0.f};
#pragma unroll
    for (int kt = 0; kt < 8; ++kt) {
      const h8 a0 = *(const h8*)&in[l15 * AROW + kt * 32 + lq * 8];
#pragma unroll
      for (int cb = 0; cb < 2; ++cb) {
        const h8 bf = *(const h8*)&wl[(size_t)((w * 2 + cb) * 8 + kt) * 512 + l * 8];
        acc[cb] = __builtin_amdgcn_mfma_f32_16x16x32_f16(a0, bf, acc[cb], 0, 0, 0);
      }
    }
#pragma unroll
    for (int cb = 0; cb < 2; ++cb)
#pragma unroll
      for (int r = 0; r < 4; ++r) {
        const float z = acc[cb][r] + bcol[cb];
        ob[(lq * 4 + r) * AROW + w * 32 + cb * 16 + l15] = (_Float16)(z * sigf(z));
      }
    __syncthreads();
  }

  // Output layer: final activations in As0 (NL=5 odd). N=64 -> waves 0..3.
  if (w < 4) {
    const _Float16* wo = wsW + WS_WOUT;
    const float bo = bout[w * 16 + l15];
    f4 acc0 = f4{0.f, 0.f, 0.f, 0.f};
#pragma unroll
    for (int kt = 0; kt < 8; ++kt) {
      const h8 a0 = *(const h8*)&As0[l15 * AROW + kt * 32 + lq * 8];
      const h8 bf = *(const h8*)&wo[(size_t)(w * 8 + kt) * 512 + l * 8];
      acc0 = __builtin_amdgcn_mfma_f32_16x16x32_f16(a0, bf, acc0, 0, 0, 0);
    }
#pragma unroll
    for (int r = 0; r < 4; ++r)
      __builtin_nontemporal_store(acc0[r] + bo,
          &out[(size_t)(rbase + lq * 4 + r) * DOUT + w * 16 + l15]);
  }
}

// ------------------------------- launcher ----------------------------------
extern "C" void kernel_launch(void* const* d_in, const int* in_sizes, int n_in,
                              void* d_out, int out_size, void* d_ws, size_t ws_size,
                              hipStream_t stream)
{
  const float* traj = (const float*)d_in[0];
  const float* acts = (const float*)d_in[1];
  const float* Wi   = (const float*)d_in[2];
  const float* Wh   = (const float*)d_in[3];
  const float* bh   = (const float*)d_in[4];
  const float* mlpb_ = nullptr; (void)mlpb_;
  const float* mlpW = (const float*)d_in[5];
  const float* mlpb = (const float*)d_in[6];
  const float* Wout = (const float*)d_in[7];
  const float* bout = (const float*)d_in[8];
  _Float16* wsW = (_Float16*)d_ws;   // needs 1,409,024 bytes of workspace

  (void)hipFuncSetAttribute((const void*)lstm_kernel,
                            hipFuncAttributeMaxDynamicSharedMemorySize, LDS_BYTES);

  repack_kernel<<<344, 256, 0, stream>>>(Wi, Wh, mlpW, Wout, wsW);
  lstm_kernel<<<NWG, NTHR, LDS_BYTES, stream>>>(traj, acts, bh, mlpb, bout, wsW, (float*)d_out);
}

// Round 9
// 330.269 us; speedup vs baseline: 5.2255x; 1.0058x over previous
//
#include <hip/hip_runtime.h>
#include <hip/hip_fp16.h>

// ---------------------------------------------------------------------------
// DeterministicLSTMSensorBasedForwardDynamics on MI355X (gfx950) — round 17
//
// r16 post-mortem: nontemporal activations = clean null (264 vs 261 us) ->
// L2 eviction refuted. Status: latency-cover sufficient (r9/r11), byte-
// reduction weakly coupled (r11), eviction null (r16), scheduling all null.
// No roofline binds (MfmaUtil 25%, HBM 2%, per-XCD L2 ~55%).
//
// Last untested theory: L2 SAME-ADDRESS HOTSPOTTING. All 256 WGs run in
// near-lockstep and wave w of EVERY WG streams the SAME blocks in the SAME
// order -> 32 CUs/XCD hammer the same few L2 lines at any instant -> those
// requests serialize at one L2 slice while others idle -> effective L2 BW
// collapses; ring stalls look like latency no depth fixes (r11 consistent).
//
// Round 17 = r16 + per-WG column-phase rotation (ONE variable):
//   wave w of WG b owns gate-column group nb = (w + b) & 7 (pure bijection
//   inside the WG: bias, Wc/rw staging, stream base, h-write columns follow
//   nb; panel layout canonical; MLP untouched). Spreads the 8 column phases
//   across WGs -> ~8x less same-line concurrency, stream spread over the
//   full 704 KB. Zero extra hot-loop instructions.
// Prediction: theory right -> ~200-235 us, MfmaUtil 29-33%, FETCH ~39 MB,
// WRITE ~1 MB, conflicts 4.87M. Null (255-270) -> all memory+scheduling
// theories exhausted, no binding counter -> declare structural bound.
// ---------------------------------------------------------------------------

typedef _Float16 h8 __attribute__((ext_vector_type(8)));
typedef _Float16 hv4 __attribute__((ext_vector_type(4)));
typedef float f4 __attribute__((ext_vector_type(4)));

#define NB    4096
#define TSEQ  50
#define DOBS  64
#define DACT  16
#define HD    256
#define DOUT  64
#define NL    5

#define NKT   11        // K-tiles of 32 covering 352 = 80 (x) + 256 (h) + 16 pad
#define AROW  360       // LDS A-row stride in halves
#define MTILE 16
#define NWG   (NB / MTILE)   // 256
#define NTHR  512            // 8 waves

// ws layout in halves (written by repack_kernel)
#define WS_MLP   (704 * 512)
#define WS_WOUT  (WS_MLP + 640 * 512)

// LDS layout (halves): As0 | As1 | Wcache(8 waves x WCB blocks)
#define LDS_AS     (MTILE * AROW)      // 5760 per panel
#define LDS_WCOFF  (2 * LDS_AS)        // 11520
#define WCB        16                  // LDS-resident blocks per wave (cb0 kt6..9)
#define LDS_HALVES (LDS_WCOFF + 8 * WCB * 512)   // 77056
#define LDS_BYTES  (LDS_HALVES * 2)              // 154112  (<= 160 KiB)
static_assert(LDS_BYTES <= 160 * 1024, "LDS overflow");

// streaming: cb1 kt0..10 (44) + cb0 kt10 (4) = 48 blocks/wave/step,
// through an 8-slot ring that persists ACROSS steps (48 % 8 == 0).
#define SB_P     8
#define NSTREAM  48

// Barrier that does NOT drain vmcnt: cross-wave data dependencies at the
// t-loop barrier are ds_write-only (h and x panels), covered by lgkmcnt(0).
// In-flight global loads (stream ring, x prefetch) target private VGPRs and
// are synchronized by their own vmcnt-before-use waits -> legal to keep
// flying across s_barrier.
__device__ __forceinline__ void lds_barrier() {
  asm volatile("s_waitcnt lgkmcnt(0)\n\ts_barrier" ::: "memory");
}

// sigmoid via native v_exp_f32 + v_rcp_f32 (1-ulp; fp16 weights dominate err).
__device__ __forceinline__ float sigf(float x) {
  const float e = __builtin_amdgcn_exp2f(x * -1.44269504088896f);
  return __builtin_amdgcn_rcpf(1.f + e);
}

// stream order c -> block offset (halves) rel. to wave base (nb*2*NKT*512):
//   c in [0,44):  cb1, kt = c>>2, g = c&3   -> ((g*16+1)*NKT + kt)*512
//   c in [44,48): cb0 kt10, g = c-44        -> ((g*16+0)*NKT + 10)*512
__device__ constexpr int soff(int c) {
  if (c < 44) { const int g = c & 3, kt = c >> 2; return ((g * 16 + 1) * NKT + kt) * 512; }
  const int g = c - 44; return ((g * 16) * NKT + 10) * 512;
}

// --------------------------- weight repack ---------------------------------
__global__ void __launch_bounds__(256) repack_kernel(
    const float* __restrict__ Wi, const float* __restrict__ Wh,
    const float* __restrict__ mlpW, const float* __restrict__ Wout,
    _Float16* __restrict__ wsW)
{
  const int gt  = blockIdx.x * 256 + threadIdx.x;
  const int gb  = gt >> 6;
  const int l   = gt & 63;
  const int l15 = l & 15;
  const int kb  = (l >> 4) * 8;
  h8 v;
  if (gb < 704) {                       // LSTM: Wcat[k][n], k<80 -> Wi, k<336 -> Wh, else 0
    const int nt = gb / NKT, kt = gb - nt * NKT;
    const int n  = nt * 16 + l15;
#pragma unroll
    for (int j = 0; j < 8; ++j) {
      const int k = kt * 32 + kb + j;
      float s = 0.f;
      if (k < 80)       s = Wi[k * 1024 + n];
      else if (k < 336) s = Wh[(k - 80) * 1024 + n];
      v[j] = (_Float16)s;
    }
  } else if (gb < 1344) {               // MLP layer weights [5][256][256]
    const int b2 = gb - 704;
    const int L  = b2 >> 7, rr = b2 & 127;
    const int nt = rr >> 3, kt = rr & 7;
    const int n  = nt * 16 + l15;
#pragma unroll
    for (int j = 0; j < 8; ++j) {
      const int k = kt * 32 + kb + j;
      v[j] = (_Float16)mlpW[(size_t)L * 65536 + k * 256 + n];
    }
  } else {                              // Wout [256][64]
    const int b3 = gb - 1344;
    const int nt = b3 >> 3, kt = b3 & 7;
    const int n  = nt * 16 + l15;
#pragma unroll
    for (int j = 0; j < 8; ++j) {
      const int k = kt * 32 + kb + j;
      v[j] = (_Float16)Wout[k * 64 + n];
    }
  }
  *(h8*)&wsW[(size_t)gb * 512 + l * 8] = v;
}

// ------------------------------ main kernel --------------------------------
__global__ void __launch_bounds__(NTHR, 2) lstm_kernel(
    const float* __restrict__ traj, const float* __restrict__ acts,
    const float* __restrict__ bh,   const float* __restrict__ mlpb,
    const float* __restrict__ bout, const _Float16* __restrict__ wsW,
    float* __restrict__ out)
{
  extern __shared__ __align__(16) _Float16 lds[];
  _Float16* As0 = lds;
  _Float16* As1 = lds + LDS_AS;
  _Float16* Wc  = lds + LDS_WCOFF;

  const int tid = threadIdx.x;
  const int w   = tid >> 6;        // physical wave 0..7
  const int l   = tid & 63;
  const int l15 = l & 15;
  const int lq  = l >> 4;
  const int rbase = blockIdx.x * MTILE;

  // L2-hotspot decorrelation: wave w of WG b owns h-cols [32*nb, 32*nb+32),
  // nb = (w+b)&7. Pure bijection inside the WG; panel layout stays canonical.
  const int nb  = (w + (int)blockIdx.x) & 7;

  // Zero both A panels (h starts 0; pad cols 336..359 stay 0 forever).
  for (int i = tid; i < 2 * LDS_AS; i += NTHR) lds[i] = (_Float16)0.f;

  // LDS-resident: 16 blocks/wave = (cb0, kt6..9, g0..3) for column group nb
#pragma unroll
  for (int j = 0; j < WCB; ++j) {
    const int g = j & 3, kt = 6 + (j >> 2);
    const h8 v = *(const h8*)&wsW[(size_t)((g * 16 + nb * 2) * NKT + kt) * 512 + l * 8];
    *(h8*)&Wc[(w * WCB + j) * 512 + l * 8] = v;
  }

  // Register-resident: 24 blocks/wave = (cb0, kt0..5, g0..3) — AGPR-backed.
  h8 rw[24];
#pragma unroll
  for (int kt = 0; kt < 6; ++kt)
#pragma unroll
    for (int g = 0; g < 4; ++g)
      rw[kt * 4 + g] = *(const h8*)&wsW[(size_t)((g * 16 + nb * 2) * NKT + kt) * 512 + l * 8];

  // Persistent cell state + biases
  float c[2][4];
#pragma unroll
  for (int cb = 0; cb < 2; ++cb)
#pragma unroll
    for (int r = 0; r < 4; ++r) c[cb][r] = 0.f;

  float bias[4][2];
#pragma unroll
  for (int g = 0; g < 4; ++g) {
    bias[g][0] = bh[g * 256 + nb * 32 + l15];
    bias[g][1] = bh[g * 256 + nb * 32 + 16 + l15];
  }

  __syncthreads();

  // Stage x_0 into As0 cols 0..79 (traj via waves 0-3, acts via waves 4-7).
  // Nontemporal: keep activations out of L2 (r16: neutral but harmless).
  if (tid < 256) {
    const int r = tid >> 4, q = tid & 15;
    const f4 v = __builtin_nontemporal_load(
        (const f4*)&traj[(size_t)(rbase + r) * (TSEQ * DOBS) + q * 4]);
    hv4 hx = { (_Float16)v.x, (_Float16)v.y, (_Float16)v.z, (_Float16)v.w };
    *(hv4*)&As0[r * AROW + q * 4] = hx;
  } else {
    const int r = (tid - 256) >> 4, q = (tid - 256) & 15;
    As0[r * AROW + 64 + q] = (_Float16)__builtin_nontemporal_load(
        &acts[(size_t)(rbase + r) * (TSEQ * DACT) + q]);
  }
  __syncthreads();

  unsigned long long wbits = (unsigned long long)(const void*)wsW;

  // Persistent 8-slot stream ring. Primed once here; thereafter each step's
  // last 8 refills prime the next step (stream order periodic mod 48).
  h8 sb[SB_P];
  {
    const _Float16* wlb0 = wsW + (size_t)(nb * 2 * NKT) * 512 + l * 8;
#pragma unroll
    for (int cc = 0; cc < SB_P; ++cc) sb[cc] = *(const h8*)&wlb0[soff(cc)];
  }

  auto step = [&](int t, const _Float16* buf, _Float16* nbuf) {
    // Memory clobber: stream loads can't be hoisted/CSE'd across steps and
    // rw[] can't be legally rematerialized from wsW.
    asm volatile("" : "+s"(wbits) : : "memory");
    const _Float16* wst = (const _Float16*)wbits;
    const _Float16* wlb = wst + (size_t)(nb * 2 * NKT) * 512 + l * 8;

    // x(t+1): load to registers now (nontemporal), store to LDS at end.
    f4 xv; float xa;
    const bool havex = (t + 1 < TSEQ);
    if (havex) {
      if (tid < 256) {
        const int r = tid >> 4, q = tid & 15;
        xv = __builtin_nontemporal_load(
            (const f4*)&traj[(size_t)(rbase + r) * (TSEQ * DOBS) + (t + 1) * DOBS + q * 4]);
      } else {
        const int r = (tid - 256) >> 4, q = (tid - 256) & 15;
        xa = __builtin_nontemporal_load(
            &acts[(size_t)(rbase + r) * (TSEQ * DACT) + (t + 1) * DACT + q]);
      }
    }

    // ---------------- fused K-loop: cb0 (on-chip) + cb1 (streamed) ---------
    f4 acc0[4], acc1[4];
#pragma unroll
    for (int g = 0; g < 4; ++g) {
      acc0[g] = f4{0.f, 0.f, 0.f, 0.f};
      acc1[g] = f4{0.f, 0.f, 0.f, 0.f};
    }

#pragma unroll
    for (int kt = 0; kt < NKT; ++kt) {
      const h8 a0 = *(const h8*)&buf[l15 * AROW + kt * 32 + lq * 8];
#pragma unroll
      for (int g = 0; g < 4; ++g) {
        // cb0 fragment: registers (kt<6), LDS cache (kt6..9), stream (kt10,
        // ring slots 4..7 = positions 44..47, refilled at kt9).
        h8 bf0;
        if (kt < 6)       bf0 = rw[kt * 4 + g];
        else if (kt < 10) bf0 = *(const h8*)&Wc[(w * WCB + (kt - 6) * 4 + g) * 512 + l * 8];
        else              bf0 = sb[4 + g];
        acc0[g] = __builtin_amdgcn_mfma_f32_16x16x32_f16(a0, bf0, acc0[g], 0, 0, 0);

        // cb1 fragment: stream position cc; refill slot with position cc+8
        // (mod 48 -> the last 8 refills fetch NEXT step's first blocks).
        const int cc = kt * 4 + g;
        acc1[g] = __builtin_amdgcn_mfma_f32_16x16x32_f16(a0, sb[cc % SB_P], acc1[g], 0, 0, 0);
        sb[cc % SB_P] = *(const h8*)&wlb[soff((cc + SB_P) % NSTREAM)];
        if (kt == 10) {   // also re-prime the cb0-kt10 slots for next step
          sb[4 + g] = *(const h8*)&wlb[soff(4 + g)];
        }
      }
    }

    // ---------------- cell update (fused-rcp: 5 exp + 3 rcp per chain) -----
    const float KE = -1.44269504088896f;   // -log2(e)
    {
      const int colh = 80 + nb * 32 + l15;   // cb=0
#pragma unroll
      for (int r = 0; r < 4; ++r) {
        const float zi = acc0[0][r] + bias[0][0];
        const float zf = acc0[1][r] + bias[1][0];
        const float zg = acc0[2][r] + bias[2][0];
        const float zo = acc0[3][r] + bias[3][0];
        const float ei = __builtin_amdgcn_exp2f(zi * KE);
        const float ef = __builtin_amdgcn_exp2f(zf * KE);
        const float eg = __builtin_amdgcn_exp2f(zg * KE);
        const float eo = __builtin_amdgcn_exp2f(zo * KE);
        const float fg = __builtin_amdgcn_rcpf(1.f + ef);
        const float igg = zg * __builtin_amdgcn_rcpf((1.f + ei) * (1.f + eg)); // i*g
        const float cn = fg * c[0][r] + igg;
        c[0][r] = cn;
        const float ec = __builtin_amdgcn_exp2f(cn * KE);
        const float hn = cn * __builtin_amdgcn_rcpf((1.f + eo) * (1.f + ec)); // o*silu(c)
        nbuf[(lq * 4 + r) * AROW + colh] = (_Float16)hn;
      }
    }
    {
      const int colh = 80 + nb * 32 + 16 + l15;   // cb=1
#pragma unroll
      for (int r = 0; r < 4; ++r) {
        const float zi = acc1[0][r] + bias[0][1];
        const float zf = acc1[1][r] + bias[1][1];
        const float zg = acc1[2][r] + bias[2][1];
        const float zo = acc1[3][r] + bias[3][1];
        const float ei = __builtin_amdgcn_exp2f(zi * KE);
        const float ef = __builtin_amdgcn_exp2f(zf * KE);
        const float eg = __builtin_amdgcn_exp2f(zg * KE);
        const float eo = __builtin_amdgcn_exp2f(zo * KE);
        const float fg = __builtin_amdgcn_rcpf(1.f + ef);
        const float igg = zg * __builtin_amdgcn_rcpf((1.f + ei) * (1.f + eg));
        const float cn = fg * c[1][r] + igg;
        c[1][r] = cn;
        const float ec = __builtin_amdgcn_exp2f(cn * KE);
        const float hn = cn * __builtin_amdgcn_rcpf((1.f + eo) * (1.f + ec));
        nbuf[(lq * 4 + r) * AROW + colh] = (_Float16)hn;
      }
    }

    // Deferred x(t+1) store into nbuf cols 0..79.
    if (havex) {
      if (tid < 256) {
        const int r = tid >> 4, q = tid & 15;
        hv4 hx = { (_Float16)xv.x, (_Float16)xv.y, (_Float16)xv.z, (_Float16)xv.w };
        *(hv4*)&nbuf[r * AROW + q * 4] = hx;
      } else {
        const int r = (tid - 256) >> 4, q = (tid - 256) & 15;
        nbuf[r * AROW + 64 + q] = (_Float16)xa;
      }
    }
  };

#pragma unroll 1
  for (int t = 0; t < TSEQ; t += 2) {
    step(t, As0, As1);
    lds_barrier();           // LDS-only: stream ring stays in flight
    step(t + 1, As1, As0);
    lds_barrier();
  }

  // ---------------- MLP head ----------------
  // Final h in As0 cols 80..335 (canonical layout). Move to As1 cols 0..255.
  for (int i = tid; i < MTILE * HD; i += NTHR) {
    const int r = i >> 8, cc = i & 255;
    As1[r * AROW + cc] = As0[r * AROW + 80 + cc];
  }
  __syncthreads();

#pragma unroll 1
  for (int L = 0; L < NL; ++L) {
    const _Float16* in = (L & 1) ? As0 : As1;
    _Float16*       ob = (L & 1) ? As1 : As0;
    const _Float16* wl = wsW + WS_MLP + (size_t)L * (128 * 512);
    float bcol[2];
    bcol[0] = mlpb[L * HD + w * 32 + l15];
    bcol[1] = mlpb[L * HD + w * 32 + 16 + l15];

    f4 acc[2];
    acc[0] = f4{0.f, 0.f, 0.f, 0.f};
    acc[1] = f4{0.f, 0.f, 0.f, 0.f};
#pragma unroll
    for (int kt = 0; kt < 8; ++kt) {
      const h8 a0 = *(const h8*)&in[l15 * AROW + kt * 32 + lq * 8];
#pragma unroll
      for (int cb = 0; cb < 2; ++cb) {
        const h8 bf = *(const h8*)&wl[(size_t)((w * 2 + cb) * 8 + kt) * 512 + l * 8];
        acc[cb] = __builtin_amdgcn_mfma_f32_16x16x32_f16(a0, bf, acc[cb], 0, 0, 0);
      }
    }
#pragma unroll
    for (int cb = 0; cb < 2; ++cb)
#pragma unroll
      for (int r = 0; r < 4; ++r) {
        const float z = acc[cb][r] + bcol[cb];
        ob[(lq * 4 + r) * AROW + w * 32 + cb * 16 + l15] = (_Float16)(z * sigf(z));
      }
    __syncthreads();
  }

  // Output layer: final activations in As0 (NL=5 odd). N=64 -> waves 0..3.
  if (w < 4) {
    const _Float16* wo = wsW + WS_WOUT;
    const float bo = bout[w * 16 + l15];
    f4 acc0 = f4{0.f, 0.f, 0.f, 0.f};
#pragma unroll
    for (int kt = 0; kt < 8; ++kt) {
      const h8 a0 = *(const h8*)&As0[l15 * AROW + kt * 32 + lq * 8];
      const h8 bf = *(const h8*)&wo[(size_t)(w * 8 + kt) * 512 + l * 8];
      acc0 = __builtin_amdgcn_mfma_f32_16x16x32_f16(a0, bf, acc0, 0, 0, 0);
    }
#pragma unroll
    for (int r = 0; r < 4; ++r)
      __builtin_nontemporal_store(acc0[r] + bo,
          &out[(size_t)(rbase + lq * 4 + r) * DOUT + w * 16 + l15]);
  }
}

// ------------------------------- launcher ----------------------------------
extern "C" void kernel_launch(void* const* d_in, const int* in_sizes, int n_in,
                              void* d_out, int out_size, void* d_ws, size_t ws_size,
                              hipStream_t stream)
{
  const float* traj = (const float*)d_in[0];
  const float* acts = (const float*)d_in[1];
  const float* Wi   = (const float*)d_in[2];
  const float* Wh   = (const float*)d_in[3];
  const float* bh   = (const float*)d_in[4];
  const float* mlpW = (const float*)d_in[5];
  const float* mlpb = (const float*)d_in[6];
  const float* Wout = (const float*)d_in[7];
  const float* bout = (const float*)d_in[8];
  _Float16* wsW = (_Float16*)d_ws;   // needs 1,409,024 bytes of workspace

  (void)hipFuncSetAttribute((const void*)lstm_kernel,
                            hipFuncAttributeMaxDynamicSharedMemorySize, LDS_BYTES);

  repack_kernel<<<344, 256, 0, stream>>>(Wi, Wh, mlpW, Wout, wsW);
  lstm_kernel<<<NWG, NTHR, LDS_BYTES, stream>>>(traj, acts, bh, mlpb, bout, wsW, (float*)d_out);
}